// Round 4
// baseline (22233.807 us; speedup 1.0000x reference)
//
#include <hip/hip_runtime.h>
#include <math.h>

#define N_NODES 50000
#define E_EDGES 1600000
#define F_INDIM 512
#define H_DIM   256
#define C_OUT   121
#define L_LAYERS 4

typedef unsigned short u16;

__device__ __forceinline__ float bf2f(u16 h) {
    return __uint_as_float(((unsigned int)h) << 16);
}
__device__ __forceinline__ u16 f2bf(float f) {
    unsigned int u = __float_as_uint(f);
    unsigned int r = u + 0x7FFFu + ((u >> 16) & 1u);   // round-to-nearest-even
    return (u16)(r >> 16);
}

// ---------------- zero an fp32 buffer ----------------
__global__ void zerof_kernel(float* __restrict__ p, int n) {
    int i = blockIdx.x * blockDim.x + threadIdx.x;
    if (i < n) p[i] = 0.f;
}

// ---------------- lin0: X = X0 = relu(x_in @ W + b), 8 rows/block ----------------
__global__ void lin0_kernel(const float* __restrict__ A, const float* __restrict__ W,
                            const float* __restrict__ b,
                            u16* __restrict__ X, u16* __restrict__ X0) {
    const int col  = threadIdx.x;          // 0..255
    const int row0 = blockIdx.x * 8;       // 50000/8 = 6250 exact
    float acc[8] = {0.f, 0.f, 0.f, 0.f, 0.f, 0.f, 0.f, 0.f};
    for (int k = 0; k < F_INDIM; ++k) {
        float w = W[(long)k * H_DIM + col];
        #pragma unroll
        for (int r = 0; r < 8; ++r)
            acc[r] += A[(long)(row0 + r) * F_INDIM + k] * w;
    }
    float bias = b[col];
    #pragma unroll
    for (int r = 0; r < 8; ++r) {
        float v = fmaxf(acc[r] + bias, 0.f);
        u16 h = f2bf(v);
        long idx = (long)(row0 + r) * H_DIM + col;
        X[idx] = h;
        X0[idx] = h;
    }
}

// ---------------- edge-parallel scatter-add: Hf += w * X[src] ----------------
// 4 edges per 256-thread block; 64 lanes per edge, 4 feats per lane
__global__ void scatter_add_kernel(const int* __restrict__ esrc, const int* __restrict__ edst,
                                   const float* __restrict__ ew, const u16* __restrict__ X,
                                   float* __restrict__ Hf) {
    int t = blockIdx.x * blockDim.x + threadIdx.x;
    int e = t >> 6;
    int lane = t & 63;
    if (e >= E_EDGES) return;
    int s = esrc[e];
    int d = edst[e];
    float w = ew[e];
    ushort4 v = *reinterpret_cast<const ushort4*>(X + (long)s * H_DIM + lane * 4);
    float* hp = Hf + (long)d * H_DIM + lane * 4;
    atomicAdd(hp + 0, w * bf2f(v.x));
    atomicAdd(hp + 1, w * bf2f(v.y));
    atomicAdd(hp + 2, w * bf2f(v.z));
    atomicAdd(hp + 3, w * bf2f(v.w));
}

// ---------------- combine: Hf = 0.5*Hf + 0.5*X0 ----------------
__global__ void combine_kernel(float* __restrict__ Hf, const u16* __restrict__ X0, int n) {
    int i = blockIdx.x * blockDim.x + threadIdx.x;
    if (i < n) Hf[i] = 0.5f * Hf[i] + 0.5f * bf2f(X0[i]);
}

// ---------------- conv: X = relu((1-b)*Hf + b*(Hf@W) + X), 8 rows/block ----------------
__global__ void conv_kernel(const float* __restrict__ Hf, const float* __restrict__ W,
                            u16* __restrict__ X, float beta) {
    const int col  = threadIdx.x;          // 0..255
    const int row0 = blockIdx.x * 8;
    float acc[8] = {0.f, 0.f, 0.f, 0.f, 0.f, 0.f, 0.f, 0.f};
    for (int k = 0; k < H_DIM; ++k) {
        float w = W[(long)k * H_DIM + col];
        #pragma unroll
        for (int r = 0; r < 8; ++r)
            acc[r] += Hf[(long)(row0 + r) * H_DIM + k] * w;
    }
    #pragma unroll
    for (int r = 0; r < 8; ++r) {
        long idx = (long)(row0 + r) * H_DIM + col;
        float h = Hf[idx];
        float v = (1.f - beta) * h + beta * acc[r] + bf2f(X[idx]);
        X[idx] = f2bf(fmaxf(v, 0.f));
    }
}

// ---------------- lin1: out = X @ W + b, 8 rows/block, 128 threads ----------------
__global__ void lin1_kernel(const u16* __restrict__ X, const float* __restrict__ W,
                            const float* __restrict__ b, float* __restrict__ out) {
    const int col  = threadIdx.x;          // 0..127
    const int row0 = blockIdx.x * 8;
    if (col >= C_OUT) return;              // no barriers in this kernel: safe
    float acc[8] = {0.f, 0.f, 0.f, 0.f, 0.f, 0.f, 0.f, 0.f};
    for (int k = 0; k < H_DIM; ++k) {
        float w = W[(long)k * C_OUT + col];
        #pragma unroll
        for (int r = 0; r < 8; ++r)
            acc[r] += bf2f(X[(long)(row0 + r) * H_DIM + k]) * w;
    }
    float bias = b[col];
    #pragma unroll
    for (int r = 0; r < 8; ++r)
        out[(long)(row0 + r) * C_OUT + col] = acc[r] + bias;
}

extern "C" void kernel_launch(void* const* d_in, const int* in_sizes, int n_in,
                              void* d_out, int out_size, void* d_ws, size_t ws_size,
                              hipStream_t stream) {
    const float* x_in = (const float*)d_in[0];
    const int*   esrc = (const int*)d_in[1];
    const int*   edst = (const int*)d_in[2];
    const float* ew   = (const float*)d_in[3];
    const float* l0w  = (const float*)d_in[4];
    const float* l0b  = (const float*)d_in[5];
    const float* cw   = (const float*)d_in[6];
    const float* l1w  = (const float*)d_in[7];
    const float* l1b  = (const float*)d_in[8];
    float* out = (float*)d_out;
    (void)in_sizes; (void)n_in; (void)out_size;

    char* ws = (char*)d_ws;
    auto al = [](size_t x) { return (x + 255) & ~(size_t)255; };
    size_t o = 0;
    const size_t NHb = (size_t)N_NODES * H_DIM * sizeof(u16);    // 25.6 MB
    const size_t NHf = (size_t)N_NODES * H_DIM * sizeof(float);  // 51.2 MB
    u16*   X  = (u16*)(ws + o);  o += al(NHb);
    u16*   X0 = (u16*)(ws + o);  o += al(NHb);
    float* Hf = (float*)(ws + o); o += al(NHf);
    if (ws_size < o) return;   // diagnostic: clean zero-output => ws too small

    const int NH = N_NODES * H_DIM;                 // 12.8M
    const int ROWB = N_NODES / 8;                   // 6250 blocks, exact
    const int SCAT_BLOCKS = (E_EDGES * 64) / 256;   // 400000, exact

    // 1. input projection
    lin0_kernel<<<ROWB, 256, 0, stream>>>(x_in, l0w, l0b, X, X0);

    // 2. layers
    for (int l = 0; l < L_LAYERS; ++l) {
        float beta = logf(1.0f / (float)(l + 1) + 1.0f);
        zerof_kernel<<<(NH + 255) / 256, 256, 0, stream>>>(Hf, NH);
        scatter_add_kernel<<<SCAT_BLOCKS, 256, 0, stream>>>(esrc, edst, ew, X, Hf);
        combine_kernel<<<(NH + 255) / 256, 256, 0, stream>>>(Hf, X0, NH);
        conv_kernel<<<ROWB, 256, 0, stream>>>(Hf, cw + (size_t)l * H_DIM * H_DIM, X, beta);
    }

    // 3. output projection
    lin1_kernel<<<ROWB, 128, 0, stream>>>(X, l1w, l1b, out);
}

// Round 5
// 2294.492 us; speedup vs baseline: 9.6901x; 9.6901x over previous
//
#include <hip/hip_runtime.h>
#include <math.h>

#define N_NODES 50000
#define E_EDGES 1600000
#define F_INDIM 512
#define H_DIM   256
#define C_OUT   121
#define L_LAYERS 4

typedef unsigned short u16;

__device__ __forceinline__ float bf2f(u16 h) {
    return __uint_as_float(((unsigned int)h) << 16);
}
__device__ __forceinline__ u16 f2bf(float f) {
    unsigned int u = __float_as_uint(f);
    unsigned int r = u + 0x7FFFu + ((u >> 16) & 1u);   // round-to-nearest-even
    return (u16)(r >> 16);
}

// ---------------- utility ----------------
__global__ void zeroi_kernel(int* __restrict__ p, int n) {
    int i = blockIdx.x * blockDim.x + threadIdx.x;
    if (i < n) p[i] = 0;
}

// ---------------- CSR build ----------------
__global__ void hist_kernel(const int* __restrict__ dst, int* __restrict__ deg) {
    int e = blockIdx.x * blockDim.x + threadIdx.x;
    if (e < E_EDGES) {
        int d = dst[e];
        if (d >= 0 && d < N_NODES) atomicAdd(&deg[d], 1);
    }
}

// single block, 256 threads: exclusive scan of deg[N] -> row_ptr[N+1]
__global__ void scan_kernel(const int* __restrict__ deg, int* __restrict__ row_ptr) {
    __shared__ int sums[256];
    const int t = threadIdx.x;
    const int CH = (N_NODES + 255) / 256;   // 196
    const int base = t * CH;
    int s = 0;
    for (int i = 0; i < CH; ++i) {
        int idx = base + i;
        if (idx < N_NODES) s += deg[idx];
    }
    sums[t] = s;
    __syncthreads();
    for (int off = 1; off < 256; off <<= 1) {
        int v = (t >= off) ? sums[t - off] : 0;
        __syncthreads();
        sums[t] += v;
        __syncthreads();
    }
    int run = (t == 0) ? 0 : sums[t - 1];
    for (int i = 0; i < CH; ++i) {
        int idx = base + i;
        if (idx < N_NODES) { row_ptr[idx] = run; run += deg[idx]; }
    }
    if (t == 255) row_ptr[N_NODES] = run;    // == E
}

__global__ void scatter_kernel(const int* __restrict__ src, const int* __restrict__ dst,
                               const float* __restrict__ w, const int* __restrict__ row_ptr,
                               int* __restrict__ cnt, int* __restrict__ s_src,
                               float* __restrict__ s_w) {
    int e = blockIdx.x * blockDim.x + threadIdx.x;
    if (e < E_EDGES) {
        int d = dst[e];
        if (d < 0) d = 0; if (d >= N_NODES) d = N_NODES - 1;   // defensive
        int p = atomicAdd(&cnt[d], 1);
        long idx = (long)row_ptr[d] + p;
        if (idx < 0) idx = 0; if (idx >= E_EDGES) idx = E_EDGES - 1;  // defensive
        s_src[idx] = src[e];
        s_w[idx]   = w[e];
    }
}

// ------- SpMM + combine: Hb[row] = 0.5*(sum_e w*X[src]) + 0.5*X0[row] (bf16) -------
// one wave per dst row; lane owns 4 of the 256 features (8B ushort4)
__global__ __launch_bounds__(256) void spmm_kernel(
        const int* __restrict__ row_ptr, const int* __restrict__ s_src,
        const float* __restrict__ s_w, const u16* __restrict__ X,
        const u16* __restrict__ X0, u16* __restrict__ Hb) {
    int wave = threadIdx.x >> 6;
    int lane = threadIdx.x & 63;
    int row  = blockIdx.x * 4 + wave;
    if (row >= N_NODES) return;
    int beg = row_ptr[row], end = row_ptr[row + 1];
    if (beg < 0) beg = 0; if (end > E_EDGES) end = E_EDGES;   // defensive
    float a0 = 0.f, a1 = 0.f, a2 = 0.f, a3 = 0.f;
    for (int e = beg; e < end; ++e) {
        int s = s_src[e];
        if (s < 0) s = 0; if (s >= N_NODES) s = N_NODES - 1;  // defensive
        float wgt = s_w[e];
        ushort4 v = *reinterpret_cast<const ushort4*>(X + (long)s * H_DIM + lane * 4);
        a0 += wgt * bf2f(v.x); a1 += wgt * bf2f(v.y);
        a2 += wgt * bf2f(v.z); a3 += wgt * bf2f(v.w);
    }
    ushort4 x0 = *reinterpret_cast<const ushort4*>(X0 + (long)row * H_DIM + lane * 4);
    ushort4 o;
    o.x = f2bf(0.5f * a0 + 0.5f * bf2f(x0.x));
    o.y = f2bf(0.5f * a1 + 0.5f * bf2f(x0.y));
    o.z = f2bf(0.5f * a2 + 0.5f * bf2f(x0.z));
    o.w = f2bf(0.5f * a3 + 0.5f * bf2f(x0.w));
    *reinterpret_cast<ushort4*>(Hb + (long)row * H_DIM + lane * 4) = o;
}

// ---------------- lin0: X = X0 = relu(x_in @ W + b), 8 rows/block ----------------
__global__ void lin0_kernel(const float* __restrict__ A, const float* __restrict__ W,
                            const float* __restrict__ b,
                            u16* __restrict__ X, u16* __restrict__ X0) {
    const int col  = threadIdx.x;          // 0..255
    const int row0 = blockIdx.x * 8;       // 50000/8 = 6250 exact
    float acc[8] = {0.f, 0.f, 0.f, 0.f, 0.f, 0.f, 0.f, 0.f};
    for (int k = 0; k < F_INDIM; ++k) {
        float w = W[(long)k * H_DIM + col];
        #pragma unroll
        for (int r = 0; r < 8; ++r)
            acc[r] += A[(long)(row0 + r) * F_INDIM + k] * w;
    }
    float bias = b[col];
    #pragma unroll
    for (int r = 0; r < 8; ++r) {
        float v = fmaxf(acc[r] + bias, 0.f);
        u16 h = f2bf(v);
        long idx = (long)(row0 + r) * H_DIM + col;
        X[idx] = h;
        X0[idx] = h;
    }
}

// ------- conv: X = relu((1-b)*Hb + b*(Hb@W) + X), 8 rows/block, Hb bf16 -------
__global__ void conv_kernel(const u16* __restrict__ Hb, const float* __restrict__ W,
                            u16* __restrict__ X, float beta) {
    const int col  = threadIdx.x;          // 0..255
    const int row0 = blockIdx.x * 8;
    float acc[8] = {0.f, 0.f, 0.f, 0.f, 0.f, 0.f, 0.f, 0.f};
    for (int k = 0; k < H_DIM; ++k) {
        float w = W[(long)k * H_DIM + col];
        #pragma unroll
        for (int r = 0; r < 8; ++r)
            acc[r] += bf2f(Hb[(long)(row0 + r) * H_DIM + k]) * w;
    }
    #pragma unroll
    for (int r = 0; r < 8; ++r) {
        long idx = (long)(row0 + r) * H_DIM + col;
        float h = bf2f(Hb[idx]);
        float v = (1.f - beta) * h + beta * acc[r] + bf2f(X[idx]);
        X[idx] = f2bf(fmaxf(v, 0.f));
    }
}

// ---------------- lin1: out = X @ W + b, 8 rows/block, 128 threads ----------------
__global__ void lin1_kernel(const u16* __restrict__ X, const float* __restrict__ W,
                            const float* __restrict__ b, float* __restrict__ out) {
    const int col  = threadIdx.x;          // 0..127
    const int row0 = blockIdx.x * 8;
    if (col >= C_OUT) return;              // no barriers in this kernel: safe
    float acc[8] = {0.f, 0.f, 0.f, 0.f, 0.f, 0.f, 0.f, 0.f};
    for (int k = 0; k < H_DIM; ++k) {
        float w = W[(long)k * C_OUT + col];
        #pragma unroll
        for (int r = 0; r < 8; ++r)
            acc[r] += bf2f(X[(long)(row0 + r) * H_DIM + k]) * w;
    }
    float bias = b[col];
    #pragma unroll
    for (int r = 0; r < 8; ++r)
        out[(long)(row0 + r) * C_OUT + col] = acc[r] + bias;
}

extern "C" void kernel_launch(void* const* d_in, const int* in_sizes, int n_in,
                              void* d_out, int out_size, void* d_ws, size_t ws_size,
                              hipStream_t stream) {
    const float* x_in = (const float*)d_in[0];
    const int*   esrc = (const int*)d_in[1];
    const int*   edst = (const int*)d_in[2];
    const float* ew   = (const float*)d_in[3];
    const float* l0w  = (const float*)d_in[4];
    const float* l0b  = (const float*)d_in[5];
    const float* cw   = (const float*)d_in[6];
    const float* l1w  = (const float*)d_in[7];
    const float* l1b  = (const float*)d_in[8];
    float* out = (float*)d_out;
    (void)in_sizes; (void)n_in; (void)out_size;

    char* ws = (char*)d_ws;
    auto al = [](size_t x) { return (x + 255) & ~(size_t)255; };
    size_t o = 0;
    const size_t NHb = (size_t)N_NODES * H_DIM * sizeof(u16);    // 25.6 MB
    u16* X  = (u16*)(ws + o);  o += al(NHb);
    u16* X0 = (u16*)(ws + o);  o += al(NHb);
    u16* Hb = (u16*)(ws + o);  o += al(NHb);
    int* row_ptr = (int*)(ws + o); o += al((N_NODES + 1) * sizeof(int));
    int* cnt     = (int*)(ws + o); o += al((size_t)N_NODES * sizeof(int));
    int* s_src   = (int*)(ws + o); o += al((size_t)E_EDGES * sizeof(int));
    float* s_w   = (float*)(ws + o); o += al((size_t)E_EDGES * sizeof(float));
    if (ws_size < o) return;   // diagnostic: clean zero-output => ws too small

    const int ROWB = N_NODES / 8;   // 6250, exact

    // 1. input projection
    lin0_kernel<<<ROWB, 256, 0, stream>>>(x_in, l0w, l0b, X, X0);

    // 2. CSR build (per call; deterministic work)
    zeroi_kernel<<<(N_NODES + 255) / 256, 256, 0, stream>>>(cnt, N_NODES);
    hist_kernel<<<(E_EDGES + 255) / 256, 256, 0, stream>>>(edst, cnt);
    scan_kernel<<<1, 256, 0, stream>>>(cnt, row_ptr);
    zeroi_kernel<<<(N_NODES + 255) / 256, 256, 0, stream>>>(cnt, N_NODES);
    scatter_kernel<<<(E_EDGES + 255) / 256, 256, 0, stream>>>(esrc, edst, ew, row_ptr,
                                                              cnt, s_src, s_w);

    // 3. layers
    for (int l = 0; l < L_LAYERS; ++l) {
        float beta = logf(1.0f / (float)(l + 1) + 1.0f);
        spmm_kernel<<<(N_NODES + 3) / 4, 256, 0, stream>>>(row_ptr, s_src, s_w, X, X0, Hb);
        conv_kernel<<<ROWB, 256, 0, stream>>>(Hb, cw + (size_t)l * H_DIM * H_DIM, X, beta);
    }

    // 4. output projection
    lin1_kernel<<<ROWB, 128, 0, stream>>>(X, l1w, l1b, out);
}

// Round 8
// 1484.476 us; speedup vs baseline: 14.9776x; 1.5457x over previous
//
#include <hip/hip_runtime.h>
#include <math.h>

#define N_NODES 50000
#define E_EDGES 1600000
#define F_INDIM 512
#define H_DIM   256
#define C_OUT   121
#define L_LAYERS 4

typedef unsigned short u16;
typedef short bf16x8 __attribute__((ext_vector_type(8)));
typedef float f32x4  __attribute__((ext_vector_type(4)));

__device__ __forceinline__ float bf2f(u16 h) {
    return __uint_as_float(((unsigned int)h) << 16);
}
__device__ __forceinline__ u16 f2bf(float f) {
    unsigned int u = __float_as_uint(f);
    unsigned int r = u + 0x7FFFu + ((u >> 16) & 1u);   // round-to-nearest-even
    return (u16)(r >> 16);
}

// ---------------- utility ----------------
__global__ void zeroi_kernel(int* __restrict__ p, int n) {
    int i = blockIdx.x * blockDim.x + threadIdx.x;
    if (i < n) p[i] = 0;
}

// transpose + convert: WT[n][k] = bf16(W[k][n]), rows n >= N zero-padded
__global__ void transpose_kernel(const float* __restrict__ W, u16* __restrict__ WT,
                                 int K, int N, int NPAD) {
    int i = blockIdx.x * blockDim.x + threadIdx.x;
    if (i >= NPAD * K) return;
    int n = i / K, k = i - n * K;
    WT[(long)n * K + k] = (n < N) ? f2bf(W[(long)k * N + n]) : (u16)0;
}

// ---------------- CSR build ----------------
__global__ void hist_kernel(const int* __restrict__ dst, int* __restrict__ deg) {
    int e = blockIdx.x * blockDim.x + threadIdx.x;
    if (e < E_EDGES) {
        int d = dst[e];
        if (d >= 0 && d < N_NODES) atomicAdd(&deg[d], 1);
    }
}

// single block, 256 threads: exclusive scan of deg[N] -> row_ptr[N+1]
__global__ void scan_kernel(const int* __restrict__ deg, int* __restrict__ row_ptr) {
    __shared__ int sums[256];
    const int t = threadIdx.x;
    const int CH = (N_NODES + 255) / 256;   // 196
    const int base = t * CH;
    int s = 0;
    for (int i = 0; i < CH; ++i) {
        int idx = base + i;
        if (idx < N_NODES) s += deg[idx];
    }
    sums[t] = s;
    __syncthreads();
    for (int off = 1; off < 256; off <<= 1) {
        int v = (t >= off) ? sums[t - off] : 0;
        __syncthreads();
        sums[t] += v;
        __syncthreads();
    }
    int run = (t == 0) ? 0 : sums[t - 1];
    for (int i = 0; i < CH; ++i) {
        int idx = base + i;
        if (idx < N_NODES) { row_ptr[idx] = run; run += deg[idx]; }
    }
    if (t == 255) row_ptr[N_NODES] = run;    // == E
}

__global__ void scatter_kernel(const int* __restrict__ src, const int* __restrict__ dst,
                               const float* __restrict__ w, const int* __restrict__ row_ptr,
                               int* __restrict__ cnt, int* __restrict__ s_src,
                               float* __restrict__ s_w) {
    int e = blockIdx.x * blockDim.x + threadIdx.x;
    if (e < E_EDGES) {
        int d = dst[e];
        if (d < 0) d = 0; if (d >= N_NODES) d = N_NODES - 1;   // defensive
        int p = atomicAdd(&cnt[d], 1);
        long idx = (long)row_ptr[d] + p;
        if (idx < 0) idx = 0; if (idx >= E_EDGES) idx = E_EDGES - 1;  // defensive
        s_src[idx] = src[e];
        s_w[idx]   = w[e];
    }
}

// ------- SpMM + combine: Hb[row] = 0.5*(sum_e w*X[src]) + 0.5*X0[row] (bf16) -------
__global__ __launch_bounds__(256) void spmm_kernel(
        const int* __restrict__ row_ptr, const int* __restrict__ s_src,
        const float* __restrict__ s_w, const u16* __restrict__ X,
        const u16* __restrict__ X0, u16* __restrict__ Hb) {
    int wave = threadIdx.x >> 6;
    int lane = threadIdx.x & 63;
    int row  = blockIdx.x * 4 + wave;
    if (row >= N_NODES) return;
    int beg = row_ptr[row], end = row_ptr[row + 1];
    if (beg < 0) beg = 0; if (end > E_EDGES) end = E_EDGES;   // defensive
    float a0 = 0.f, a1 = 0.f, a2 = 0.f, a3 = 0.f;
    for (int e = beg; e < end; ++e) {
        int s = s_src[e];
        if (s < 0) s = 0; if (s >= N_NODES) s = N_NODES - 1;  // defensive
        float wgt = s_w[e];
        ushort4 v = *reinterpret_cast<const ushort4*>(X + (long)s * H_DIM + lane * 4);
        a0 += wgt * bf2f(v.x); a1 += wgt * bf2f(v.y);
        a2 += wgt * bf2f(v.z); a3 += wgt * bf2f(v.w);
    }
    ushort4 x0 = *reinterpret_cast<const ushort4*>(X0 + (long)row * H_DIM + lane * 4);
    ushort4 o;
    o.x = f2bf(0.5f * a0 + 0.5f * bf2f(x0.x));
    o.y = f2bf(0.5f * a1 + 0.5f * bf2f(x0.y));
    o.z = f2bf(0.5f * a2 + 0.5f * bf2f(x0.z));
    o.w = f2bf(0.5f * a3 + 0.5f * bf2f(x0.w));
    *reinterpret_cast<ushort4*>(Hb + (long)row * H_DIM + lane * 4) = o;
}

// ---------------- MFMA GEMM: C[M x (4*NT*16)] = A[M x K] @ WT^T ----------------
// block = 4 waves; tile M=16, wave w covers cols [w*NT*16, (w+1)*NT*16)
// A frag: lane l holds A[bm + (l&15)][k0 + (l>>4)*8 + j], j=0..7 (16B contiguous)
// B frag: lane l holds WT[col0 + (l&15)][k0 + (l>>4)*8 + j]   (16B contiguous)
// C/D   : col = l&15 (+col0), row = (l>>4)*4 + r (+bm)   [m89-verified layout]
// MODE 0 (lin0): A fp32; X=X0=relu(acc+bias)
// MODE 1 (conv): A=Hb bf16; X=relu((1-beta)*Hb + beta*acc + X)
// MODE 2 (lin1): A=X bf16; out=acc+bias for col<C_OUT
template <int K, int NT, int MODE>
__global__ __launch_bounds__(256) void mfma_gemm_kernel(
        const void* __restrict__ Aptr, const u16* __restrict__ WT,
        const float* __restrict__ bias, const u16* __restrict__ Hb,
        u16* __restrict__ X, u16* __restrict__ X0, float* __restrict__ out,
        float beta) {
    const int w  = threadIdx.x >> 6;
    const int l  = threadIdx.x & 63;
    const int hi = l >> 4, lo = l & 15;
    const int bm = blockIdx.x * 16;
    const int col0 = w * (NT * 16);

    f32x4 acc[NT];
    #pragma unroll
    for (int t = 0; t < NT; ++t) acc[t] = (f32x4){0.f, 0.f, 0.f, 0.f};

    for (int k0 = 0; k0 < K; k0 += 32) {
        bf16x8 a;
        if (MODE == 0) {
            const float* ap = (const float*)Aptr + (long)(bm + lo) * K + k0 + hi * 8;
            float4 f0 = *reinterpret_cast<const float4*>(ap);
            float4 f1 = *reinterpret_cast<const float4*>(ap + 4);
            a[0] = (short)f2bf(f0.x); a[1] = (short)f2bf(f0.y);
            a[2] = (short)f2bf(f0.z); a[3] = (short)f2bf(f0.w);
            a[4] = (short)f2bf(f1.x); a[5] = (short)f2bf(f1.y);
            a[6] = (short)f2bf(f1.z); a[7] = (short)f2bf(f1.w);
        } else {
            a = *reinterpret_cast<const bf16x8*>(
                    (const u16*)Aptr + (long)(bm + lo) * K + k0 + hi * 8);
        }
        #pragma unroll
        for (int t = 0; t < NT; ++t) {
            bf16x8 b = *reinterpret_cast<const bf16x8*>(
                    WT + (long)(col0 + t * 16 + lo) * K + k0 + hi * 8);
            acc[t] = __builtin_amdgcn_mfma_f32_16x16x32_bf16(a, b, acc[t], 0, 0, 0);
        }
    }

    #pragma unroll
    for (int t = 0; t < NT; ++t) {
        const int col = col0 + t * 16 + lo;
        #pragma unroll
        for (int r = 0; r < 4; ++r) {
            const int row = bm + hi * 4 + r;
            float v = acc[t][r];
            if (MODE == 0) {
                v = fmaxf(v + bias[col], 0.f);
                u16 h = f2bf(v);
                long idx = (long)row * H_DIM + col;
                X[idx] = h; X0[idx] = h;
            } else if (MODE == 1) {
                long idx = (long)row * H_DIM + col;
                float hv = bf2f(Hb[idx]);
                float xv = bf2f(X[idx]);
                v = (1.f - beta) * hv + beta * v + xv;
                X[idx] = f2bf(fmaxf(v, 0.f));
            } else {
                if (col < C_OUT) out[(long)row * C_OUT + col] = v + bias[col];
            }
        }
    }
}

extern "C" void kernel_launch(void* const* d_in, const int* in_sizes, int n_in,
                              void* d_out, int out_size, void* d_ws, size_t ws_size,
                              hipStream_t stream) {
    const float* x_in = (const float*)d_in[0];
    const int*   esrc = (const int*)d_in[1];
    const int*   edst = (const int*)d_in[2];
    const float* ew   = (const float*)d_in[3];
    const float* l0w  = (const float*)d_in[4];
    const float* l0b  = (const float*)d_in[5];
    const float* cw   = (const float*)d_in[6];
    const float* l1w  = (const float*)d_in[7];
    const float* l1b  = (const float*)d_in[8];
    float* out = (float*)d_out;
    (void)in_sizes; (void)n_in; (void)out_size;

    char* ws = (char*)d_ws;
    auto al = [](size_t x) { return (x + 255) & ~(size_t)255; };
    size_t o = 0;
    const size_t NHb = (size_t)N_NODES * H_DIM * sizeof(u16);    // 25.6 MB
    u16* X  = (u16*)(ws + o);  o += al(NHb);
    u16* X0 = (u16*)(ws + o);  o += al(NHb);
    u16* Hb = (u16*)(ws + o);  o += al(NHb);
    int* row_ptr = (int*)(ws + o); o += al((N_NODES + 1) * sizeof(int));
    int* cnt     = (int*)(ws + o); o += al((size_t)N_NODES * sizeof(int));
    int* s_src   = (int*)(ws + o); o += al((size_t)E_EDGES * sizeof(int));
    float* s_w   = (float*)(ws + o); o += al((size_t)E_EDGES * sizeof(float));
    u16* WT0 = (u16*)(ws + o); o += al((size_t)H_DIM * F_INDIM * sizeof(u16));        // 256 KB
    u16* WTc = (u16*)(ws + o); o += al((size_t)L_LAYERS * H_DIM * H_DIM * sizeof(u16)); // 512 KB
    u16* WT1 = (u16*)(ws + o); o += al((size_t)128 * H_DIM * sizeof(u16));            // 64 KB
    if (ws_size < o) return;   // diagnostic: clean zero-output => ws too small

    const int MBLK = N_NODES / 16;   // 3125, exact

    // 0. weight prep: transpose + bf16-convert
    transpose_kernel<<<(H_DIM * F_INDIM + 255) / 256, 256, 0, stream>>>(
        l0w, WT0, F_INDIM, H_DIM, H_DIM);
    for (int l = 0; l < L_LAYERS; ++l)
        transpose_kernel<<<(H_DIM * H_DIM + 255) / 256, 256, 0, stream>>>(
            cw + (size_t)l * H_DIM * H_DIM, WTc + (size_t)l * H_DIM * H_DIM,
            H_DIM, H_DIM, H_DIM);
    transpose_kernel<<<(128 * H_DIM + 255) / 256, 256, 0, stream>>>(
        l1w, WT1, H_DIM, C_OUT, 128);

    // 1. input projection: X = X0 = relu(x_in @ l0w + l0b)   [MFMA]
    mfma_gemm_kernel<F_INDIM, 4, 0><<<MBLK, 256, 0, stream>>>(
        x_in, WT0, l0b, nullptr, X, X0, nullptr, 0.f);

    // 2. CSR build
    zeroi_kernel<<<(N_NODES + 255) / 256, 256, 0, stream>>>(cnt, N_NODES);
    hist_kernel<<<(E_EDGES + 255) / 256, 256, 0, stream>>>(edst, cnt);
    scan_kernel<<<1, 256, 0, stream>>>(cnt, row_ptr);
    zeroi_kernel<<<(N_NODES + 255) / 256, 256, 0, stream>>>(cnt, N_NODES);
    scatter_kernel<<<(E_EDGES + 255) / 256, 256, 0, stream>>>(esrc, edst, ew, row_ptr,
                                                              cnt, s_src, s_w);

    // 3. layers
    for (int l = 0; l < L_LAYERS; ++l) {
        float beta = logf(1.0f / (float)(l + 1) + 1.0f);
        spmm_kernel<<<(N_NODES + 3) / 4, 256, 0, stream>>>(row_ptr, s_src, s_w, X, X0, Hb);
        mfma_gemm_kernel<H_DIM, 4, 1><<<MBLK, 256, 0, stream>>>(
            Hb, WTc + (size_t)l * H_DIM * H_DIM, nullptr, Hb, X, nullptr, nullptr, beta);
    }

    // 4. output projection: out = X @ l1w + l1b   [MFMA]
    mfma_gemm_kernel<H_DIM, 2, 2><<<MBLK, 256, 0, stream>>>(
        X, WT1, l1b, nullptr, X, nullptr, out, 0.f);
}

// Round 11
// 1422.770 us; speedup vs baseline: 15.6271x; 1.0434x over previous
//
#include <hip/hip_runtime.h>
#include <math.h>

#define N_NODES 50000
#define E_EDGES 1600000
#define F_INDIM 512
#define H_DIM   256
#define C_OUT   121
#define L_LAYERS 4

typedef unsigned short u16;
typedef short bf16x8 __attribute__((ext_vector_type(8)));
typedef float f32x4  __attribute__((ext_vector_type(4)));

__device__ __forceinline__ float bf2f(u16 h) {
    return __uint_as_float(((unsigned int)h) << 16);
}
__device__ __forceinline__ u16 f2bf(float f) {
    unsigned int u = __float_as_uint(f);
    unsigned int r = u + 0x7FFFu + ((u >> 16) & 1u);   // round-to-nearest-even
    return (u16)(r >> 16);
}

// ---------------- utility ----------------
__global__ void zeroi_kernel(int* __restrict__ p, int n) {
    int i = blockIdx.x * blockDim.x + threadIdx.x;
    if (i < n) p[i] = 0;
}

// transpose + convert: WT[n][k] = bf16(W[k][n]), rows n >= N zero-padded
__global__ void transpose_kernel(const float* __restrict__ W, u16* __restrict__ WT,
                                 int K, int N, int NPAD) {
    int i = blockIdx.x * blockDim.x + threadIdx.x;
    if (i >= NPAD * K) return;
    int n = i / K, k = i - n * K;
    WT[(long)n * K + k] = (n < N) ? f2bf(W[(long)k * N + n]) : (u16)0;
}

// ---------------- CSR build ----------------
__global__ void hist_kernel(const int* __restrict__ dst, int* __restrict__ deg) {
    int e = blockIdx.x * blockDim.x + threadIdx.x;
    if (e < E_EDGES) {
        int d = dst[e];
        if (d >= 0 && d < N_NODES) atomicAdd(&deg[d], 1);
    }
}

// single block, 256 threads: exclusive scan of deg[N] -> row_ptr[N+1]
__global__ void scan_kernel(const int* __restrict__ deg, int* __restrict__ row_ptr) {
    __shared__ int sums[256];
    const int t = threadIdx.x;
    const int CH = (N_NODES + 255) / 256;   // 196
    const int base = t * CH;
    int s = 0;
    for (int i = 0; i < CH; ++i) {
        int idx = base + i;
        if (idx < N_NODES) s += deg[idx];
    }
    sums[t] = s;
    __syncthreads();
    for (int off = 1; off < 256; off <<= 1) {
        int v = (t >= off) ? sums[t - off] : 0;
        __syncthreads();
        sums[t] += v;
        __syncthreads();
    }
    int run = (t == 0) ? 0 : sums[t - 1];
    for (int i = 0; i < CH; ++i) {
        int idx = base + i;
        if (idx < N_NODES) { row_ptr[idx] = run; run += deg[idx]; }
    }
    if (t == 255) row_ptr[N_NODES] = run;    // == E
}

__global__ void scatter_kernel(const int* __restrict__ src, const int* __restrict__ dst,
                               const float* __restrict__ w, const int* __restrict__ row_ptr,
                               int* __restrict__ cnt, int* __restrict__ s_src,
                               float* __restrict__ s_w) {
    int e = blockIdx.x * blockDim.x + threadIdx.x;
    if (e < E_EDGES) {
        int d = dst[e];
        if (d < 0) d = 0; if (d >= N_NODES) d = N_NODES - 1;   // defensive
        int p = atomicAdd(&cnt[d], 1);
        long idx = (long)row_ptr[d] + p;
        if (idx < 0) idx = 0; if (idx >= E_EDGES) idx = E_EDGES - 1;  // defensive
        s_src[idx] = src[e];
        s_w[idx]   = w[e];
    }
}

// ===== fused layer: gather(A@Xin) + combine -> LDS tile -> MFMA conv -> residual =====
// block = 16 dst rows (3125 blocks), 4 waves.
// DOUBLE-BUFFERED: reads Xin (gather across all rows + residual), writes Xout only.
// (R9 wrote X in place -> inter-block race: other blocks' gathers saw updated rows.)
// Phase 1: wave w gathers rows [bm+w*4, bm+w*4+4): Hrow = 0.5*sum(w*Xin[src]) + 0.5*X0[row],
//          stored bf16 into LDS tile hs[16][256] with XOR swizzle byte^=((row&7)<<4)
//          (linear [row][512B] rows give 16-way bank conflicts on ds_read_b128 A-frags — G4).
// Phase 2: wave w computes cols [w*64,(w+1)*64) of Hb@W via 16x16x32 MFMA, K=256.
// Epilogue: Xout[row][col] = relu((1-beta)*Hb + beta*acc + Xin[row][col])
__global__ __launch_bounds__(256) void layer_kernel(
        const int* __restrict__ row_ptr, const int* __restrict__ s_src,
        const float* __restrict__ s_w, const u16* __restrict__ Xin,
        const u16* __restrict__ X0, u16* __restrict__ Xout,
        const u16* __restrict__ WT, float beta) {
    __shared__ __align__(16) u16 hs[16 * H_DIM];   // 8 KB, byte-swizzled
    const int w  = threadIdx.x >> 6;
    const int l  = threadIdx.x & 63;
    const int hi = l >> 4, lo = l & 15;
    const int bm = blockIdx.x * 16;

    // ---- phase 1: gather 4 rows per wave (loop identical to R8 spmm) ----
    for (int i = 0; i < 4; ++i) {
        const int rl  = w * 4 + i;
        const int row = bm + rl;
        int beg = row_ptr[row], end = row_ptr[row + 1];
        if (beg < 0) beg = 0; if (end > E_EDGES) end = E_EDGES;   // defensive
        float a0 = 0.f, a1 = 0.f, a2 = 0.f, a3 = 0.f;
        for (int e = beg; e < end; ++e) {
            int s = s_src[e];
            if (s < 0) s = 0; if (s >= N_NODES) s = N_NODES - 1;  // defensive
            float wgt = s_w[e];
            ushort4 v = *reinterpret_cast<const ushort4*>(Xin + (long)s * H_DIM + l * 4);
            a0 += wgt * bf2f(v.x); a1 += wgt * bf2f(v.y);
            a2 += wgt * bf2f(v.z); a3 += wgt * bf2f(v.w);
        }
        ushort4 x0 = *reinterpret_cast<const ushort4*>(X0 + (long)row * H_DIM + l * 4);
        ushort4 o;
        o.x = f2bf(0.5f * a0 + 0.5f * bf2f(x0.x));
        o.y = f2bf(0.5f * a1 + 0.5f * bf2f(x0.y));
        o.z = f2bf(0.5f * a2 + 0.5f * bf2f(x0.z));
        o.w = f2bf(0.5f * a3 + 0.5f * bf2f(x0.w));
        const int off = rl * 512 + ((l * 8) ^ ((rl & 7) << 4));   // 8B-aligned after XOR
        *reinterpret_cast<ushort4*>((char*)hs + off) = o;
    }
    __syncthreads();

    // ---- phase 2: conv GEMM on the LDS tile ----
    const int col0 = w * 64;
    f32x4 acc[4];
    #pragma unroll
    for (int t = 0; t < 4; ++t) acc[t] = (f32x4){0.f, 0.f, 0.f, 0.f};

    for (int k0 = 0; k0 < H_DIM; k0 += 32) {
        const int aoff = lo * 512 + (((k0 * 2) + hi * 16) ^ ((lo & 7) << 4));  // 16B-aligned
        bf16x8 a = *reinterpret_cast<const bf16x8*>((const char*)hs + aoff);
        #pragma unroll
        for (int t = 0; t < 4; ++t) {
            bf16x8 b = *reinterpret_cast<const bf16x8*>(
                    WT + (long)(col0 + t * 16 + lo) * H_DIM + k0 + hi * 8);
            acc[t] = __builtin_amdgcn_mfma_f32_16x16x32_bf16(a, b, acc[t], 0, 0, 0);
        }
    }

    // ---- epilogue: residual + relu -> Xout ----
    #pragma unroll
    for (int t = 0; t < 4; ++t) {
        const int col = col0 + t * 16 + lo;
        #pragma unroll
        for (int r = 0; r < 4; ++r) {
            const int rl  = hi * 4 + r;
            const int row = bm + rl;
            const int hoff = rl * 512 + ((col * 2) ^ ((rl & 7) << 4));
            float hv = bf2f(*reinterpret_cast<const u16*>((const char*)hs + hoff));
            long idx = (long)row * H_DIM + col;
            float v = (1.f - beta) * hv + beta * acc[t][r] + bf2f(Xin[idx]);
            Xout[idx] = f2bf(fmaxf(v, 0.f));
        }
    }
}

// ---------------- MFMA GEMM (lin0 / lin1), unchanged from R8 ----------------
// MODE 0 (lin0): A fp32; X=X0=relu(acc+bias)
// MODE 2 (lin1): A=X bf16; out=acc+bias for col<C_OUT
template <int K, int NT, int MODE>
__global__ __launch_bounds__(256) void mfma_gemm_kernel(
        const void* __restrict__ Aptr, const u16* __restrict__ WT,
        const float* __restrict__ bias,
        u16* __restrict__ X, u16* __restrict__ X0, float* __restrict__ out) {
    const int w  = threadIdx.x >> 6;
    const int l  = threadIdx.x & 63;
    const int hi = l >> 4, lo = l & 15;
    const int bm = blockIdx.x * 16;
    const int col0 = w * (NT * 16);

    f32x4 acc[NT];
    #pragma unroll
    for (int t = 0; t < NT; ++t) acc[t] = (f32x4){0.f, 0.f, 0.f, 0.f};

    for (int k0 = 0; k0 < K; k0 += 32) {
        bf16x8 a;
        if (MODE == 0) {
            const float* ap = (const float*)Aptr + (long)(bm + lo) * K + k0 + hi * 8;
            float4 f0 = *reinterpret_cast<const float4*>(ap);
            float4 f1 = *reinterpret_cast<const float4*>(ap + 4);
            a[0] = (short)f2bf(f0.x); a[1] = (short)f2bf(f0.y);
            a[2] = (short)f2bf(f0.z); a[3] = (short)f2bf(f0.w);
            a[4] = (short)f2bf(f1.x); a[5] = (short)f2bf(f1.y);
            a[6] = (short)f2bf(f1.z); a[7] = (short)f2bf(f1.w);
        } else {
            a = *reinterpret_cast<const bf16x8*>(
                    (const u16*)Aptr + (long)(bm + lo) * K + k0 + hi * 8);
        }
        #pragma unroll
        for (int t = 0; t < NT; ++t) {
            bf16x8 b = *reinterpret_cast<const bf16x8*>(
                    WT + (long)(col0 + t * 16 + lo) * K + k0 + hi * 8);
            acc[t] = __builtin_amdgcn_mfma_f32_16x16x32_bf16(a, b, acc[t], 0, 0, 0);
        }
    }

    #pragma unroll
    for (int t = 0; t < NT; ++t) {
        const int col = col0 + t * 16 + lo;
        #pragma unroll
        for (int r = 0; r < 4; ++r) {
            const int row = bm + hi * 4 + r;
            float v = acc[t][r];
            if (MODE == 0) {
                v = fmaxf(v + bias[col], 0.f);
                u16 h = f2bf(v);
                long idx = (long)row * H_DIM + col;
                X[idx] = h; X0[idx] = h;
            } else {
                if (col < C_OUT) out[(long)row * C_OUT + col] = v + bias[col];
            }
        }
    }
}

extern "C" void kernel_launch(void* const* d_in, const int* in_sizes, int n_in,
                              void* d_out, int out_size, void* d_ws, size_t ws_size,
                              hipStream_t stream) {
    const float* x_in = (const float*)d_in[0];
    const int*   esrc = (const int*)d_in[1];
    const int*   edst = (const int*)d_in[2];
    const float* ew   = (const float*)d_in[3];
    const float* l0w  = (const float*)d_in[4];
    const float* l0b  = (const float*)d_in[5];
    const float* cw   = (const float*)d_in[6];
    const float* l1w  = (const float*)d_in[7];
    const float* l1b  = (const float*)d_in[8];
    float* out = (float*)d_out;
    (void)in_sizes; (void)n_in; (void)out_size;

    char* ws = (char*)d_ws;
    auto al = [](size_t x) { return (x + 255) & ~(size_t)255; };
    size_t o = 0;
    const size_t NHb = (size_t)N_NODES * H_DIM * sizeof(u16);    // 25.6 MB
    u16* Xa = (u16*)(ws + o);  o += al(NHb);
    u16* Xb = (u16*)(ws + o);  o += al(NHb);
    u16* X0 = (u16*)(ws + o);  o += al(NHb);
    int* row_ptr = (int*)(ws + o); o += al((N_NODES + 1) * sizeof(int));
    int* cnt     = (int*)(ws + o); o += al((size_t)N_NODES * sizeof(int));
    int* s_src   = (int*)(ws + o); o += al((size_t)E_EDGES * sizeof(int));
    float* s_w   = (float*)(ws + o); o += al((size_t)E_EDGES * sizeof(float));
    u16* WT0 = (u16*)(ws + o); o += al((size_t)H_DIM * F_INDIM * sizeof(u16));          // 256 KB
    u16* WTc = (u16*)(ws + o); o += al((size_t)L_LAYERS * H_DIM * H_DIM * sizeof(u16)); // 512 KB
    u16* WT1 = (u16*)(ws + o); o += al((size_t)128 * H_DIM * sizeof(u16));              // 64 KB
    if (ws_size < o) return;   // diagnostic: clean zero-output => ws too small

    const int MBLK = N_NODES / 16;   // 3125, exact

    // 0. weight prep: transpose + bf16-convert
    transpose_kernel<<<(H_DIM * F_INDIM + 255) / 256, 256, 0, stream>>>(
        l0w, WT0, F_INDIM, H_DIM, H_DIM);
    for (int l = 0; l < L_LAYERS; ++l)
        transpose_kernel<<<(H_DIM * H_DIM + 255) / 256, 256, 0, stream>>>(
            cw + (size_t)l * H_DIM * H_DIM, WTc + (size_t)l * H_DIM * H_DIM,
            H_DIM, H_DIM, H_DIM);
    transpose_kernel<<<(128 * H_DIM + 255) / 256, 256, 0, stream>>>(
        l1w, WT1, H_DIM, C_OUT, 128);

    // 1. input projection: Xa = X0 = relu(x_in @ l0w + l0b)   [MFMA]
    mfma_gemm_kernel<F_INDIM, 4, 0><<<MBLK, 256, 0, stream>>>(
        x_in, WT0, l0b, Xa, X0, nullptr);

    // 2. CSR build
    zeroi_kernel<<<(N_NODES + 255) / 256, 256, 0, stream>>>(cnt, N_NODES);
    hist_kernel<<<(E_EDGES + 255) / 256, 256, 0, stream>>>(edst, cnt);
    scan_kernel<<<1, 256, 0, stream>>>(cnt, row_ptr);
    zeroi_kernel<<<(N_NODES + 255) / 256, 256, 0, stream>>>(cnt, N_NODES);
    scatter_kernel<<<(E_EDGES + 255) / 256, 256, 0, stream>>>(esrc, edst, ew, row_ptr,
                                                              cnt, s_src, s_w);

    // 3. fused layers, ping-pong Xa <-> Xb
    u16* Xcur = Xa;
    u16* Xnxt = Xb;
    for (int l = 0; l < L_LAYERS; ++l) {
        float beta = logf(1.0f / (float)(l + 1) + 1.0f);
        layer_kernel<<<MBLK, 256, 0, stream>>>(row_ptr, s_src, s_w, Xcur, X0, Xnxt,
                                               WTc + (size_t)l * H_DIM * H_DIM, beta);
        u16* tmp = Xcur; Xcur = Xnxt; Xnxt = tmp;
    }

    // 4. output projection: out = Xcur @ l1w + l1b   [MFMA]
    mfma_gemm_kernel<H_DIM, 2, 2><<<MBLK, 256, 0, stream>>>(
        Xcur, WT1, l1b, nullptr, nullptr, out);
}

// Round 12
// 1124.171 us; speedup vs baseline: 19.7780x; 1.2656x over previous
//
#include <hip/hip_runtime.h>
#include <math.h>

#define N_NODES 50000
#define E_EDGES 1600000
#define F_INDIM 512
#define H_DIM   256
#define C_OUT   121
#define L_LAYERS 4

typedef unsigned short u16;
typedef short bf16x8 __attribute__((ext_vector_type(8)));
typedef float f32x4  __attribute__((ext_vector_type(4)));

__device__ __forceinline__ float bf2f(u16 h) {
    return __uint_as_float(((unsigned int)h) << 16);
}
__device__ __forceinline__ u16 f2bf(float f) {
    unsigned int u = __float_as_uint(f);
    unsigned int r = u + 0x7FFFu + ((u >> 16) & 1u);   // round-to-nearest-even
    return (u16)(r >> 16);
}

// ---------------- utility ----------------
__global__ void zeroi_kernel(int* __restrict__ p, int n) {
    int i = blockIdx.x * blockDim.x + threadIdx.x;
    if (i < n) p[i] = 0;
}

// transpose + convert: WT[n][k] = bf16(W[k][n]), rows n >= N zero-padded
__global__ void transpose_kernel(const float* __restrict__ W, u16* __restrict__ WT,
                                 int K, int N, int NPAD) {
    int i = blockIdx.x * blockDim.x + threadIdx.x;
    if (i >= NPAD * K) return;
    int n = i / K, k = i - n * K;
    WT[(long)n * K + k] = (n < N) ? f2bf(W[(long)k * N + n]) : (u16)0;
}

// ---------------- CSR build ----------------
__global__ void hist_kernel(const int* __restrict__ dst, int* __restrict__ deg) {
    int e = blockIdx.x * blockDim.x + threadIdx.x;
    if (e < E_EDGES) {
        int d = dst[e];
        if (d >= 0 && d < N_NODES) atomicAdd(&deg[d], 1);
    }
}

// single block, 256 threads: exclusive scan of deg[N] -> row_ptr[N+1]
__global__ void scan_kernel(const int* __restrict__ deg, int* __restrict__ row_ptr) {
    __shared__ int sums[256];
    const int t = threadIdx.x;
    const int CH = (N_NODES + 255) / 256;   // 196
    const int base = t * CH;
    int s = 0;
    for (int i = 0; i < CH; ++i) {
        int idx = base + i;
        if (idx < N_NODES) s += deg[idx];
    }
    sums[t] = s;
    __syncthreads();
    for (int off = 1; off < 256; off <<= 1) {
        int v = (t >= off) ? sums[t - off] : 0;
        __syncthreads();
        sums[t] += v;
        __syncthreads();
    }
    int run = (t == 0) ? 0 : sums[t - 1];
    for (int i = 0; i < CH; ++i) {
        int idx = base + i;
        if (idx < N_NODES) { row_ptr[idx] = run; run += deg[idx]; }
    }
    if (t == 255) row_ptr[N_NODES] = run;    // == E
}

__global__ void scatter_kernel(const int* __restrict__ src, const int* __restrict__ dst,
                               const float* __restrict__ w, const int* __restrict__ row_ptr,
                               int* __restrict__ cnt, int* __restrict__ s_src,
                               float* __restrict__ s_w) {
    int e = blockIdx.x * blockDim.x + threadIdx.x;
    if (e < E_EDGES) {
        int d = dst[e];
        if (d < 0) d = 0; if (d >= N_NODES) d = N_NODES - 1;   // defensive
        int p = atomicAdd(&cnt[d], 1);
        long idx = (long)row_ptr[d] + p;
        if (idx < 0) idx = 0; if (idx >= E_EDGES) idx = E_EDGES - 1;  // defensive
        s_src[idx] = src[e];
        s_w[idx]   = w[e];
    }
}

// ===== fused layer: gather(A@Xin) + combine -> LDS tile -> MFMA conv -> residual =====
// block = 16 dst rows (3125 blocks), 4 waves. Double-buffered Xin/Xout (R10 race fix).
// Phase 1 (R12: 4-edge MLP): per row, lane covers 16B (8 feats, q=l&31), wave halves
//   process edges e+half and e+2+half concurrently -> 4 independent gather chains per
//   iteration, 8 iterations per avg row (was 32 serial). Cross-half reduce via
//   __shfl_xor(32); lanes 0-31 combine with X0 and ds_write_b128 into the swizzled
//   LDS tile (byte(f) = f*2 ^ ((rl&7)<<4) — unchanged layout).
// Phase 2: wave w computes cols [w*64,(w+1)*64) via 16x16x32 MFMA, K=256.
// Epilogue: Xout = relu((1-beta)*Hb + beta*acc + Xin).
__global__ __launch_bounds__(256) void layer_kernel(
        const int* __restrict__ row_ptr, const int* __restrict__ s_src,
        const float* __restrict__ s_w, const u16* __restrict__ Xin,
        const u16* __restrict__ X0, u16* __restrict__ Xout,
        const u16* __restrict__ WT, float beta) {
    __shared__ __align__(16) u16 hs[16 * H_DIM];   // 8 KB, byte-swizzled
    const int w  = threadIdx.x >> 6;
    const int l  = threadIdx.x & 63;
    const int hi = l >> 4, lo = l & 15;
    const int half = l >> 5;          // 0|1: which edge of the pair
    const int q    = l & 31;          // 16B chunk index within the 512B row
    const int bm = blockIdx.x * 16;

    // ---- phase 1: gather 4 rows per wave, 4 edges in flight ----
    for (int i = 0; i < 4; ++i) {
        const int rl  = w * 4 + i;
        const int row = bm + rl;
        int beg = row_ptr[row], end = row_ptr[row + 1];
        if (beg < 0) beg = 0; if (end > E_EDGES) end = E_EDGES;   // defensive
        float accA[8] = {}, accB[8] = {};
        for (int e = beg; e < end; e += 4) {
            const int eA = e + half;
            const int eB = e + 2 + half;
            const int cA = (eA < end) ? eA : end - 1;   // end-1 >= beg >= 0 here
            const int cB = (eB < end) ? eB : end - 1;
            float wA = (eA < end) ? s_w[cA] : 0.f;
            float wB = (eB < end) ? s_w[cB] : 0.f;
            int sA = s_src[cA]; if (sA < 0) sA = 0; if (sA >= N_NODES) sA = N_NODES - 1;
            int sB = s_src[cB]; if (sB < 0) sB = 0; if (sB >= N_NODES) sB = N_NODES - 1;
            bf16x8 vA = *reinterpret_cast<const bf16x8*>(Xin + (long)sA * H_DIM + q * 8);
            bf16x8 vB = *reinterpret_cast<const bf16x8*>(Xin + (long)sB * H_DIM + q * 8);
            #pragma unroll
            for (int j = 0; j < 8; ++j) {
                accA[j] += wA * bf2f((u16)vA[j]);
                accB[j] += wB * bf2f((u16)vB[j]);
            }
        }
        if (l < 32) {
            // combine halves: this lane's partner (l+32) holds the other 2 edges' sums
        }
        float acc[8];
        #pragma unroll
        for (int j = 0; j < 8; ++j) {
            float s = accA[j] + accB[j];
            s += __shfl_xor(s, 32);
            acc[j] = s;
        }
        if (l < 32) {
            bf16x8 x0 = *reinterpret_cast<const bf16x8*>(X0 + (long)row * H_DIM + q * 8);
            bf16x8 ov;
            #pragma unroll
            for (int j = 0; j < 8; ++j)
                ov[j] = (short)f2bf(0.5f * acc[j] + 0.5f * bf2f((u16)x0[j]));
            const int off = rl * 512 + ((q * 16) ^ ((rl & 7) << 4));   // 16B-aligned
            *reinterpret_cast<bf16x8*>((char*)hs + off) = ov;
        }
    }
    __syncthreads();

    // ---- phase 2: conv GEMM on the LDS tile ----
    const int col0 = w * 64;
    f32x4 acc[4];
    #pragma unroll
    for (int t = 0; t < 4; ++t) acc[t] = (f32x4){0.f, 0.f, 0.f, 0.f};

    for (int k0 = 0; k0 < H_DIM; k0 += 32) {
        const int aoff = lo * 512 + (((k0 * 2) + hi * 16) ^ ((lo & 7) << 4));  // 16B-aligned
        bf16x8 a = *reinterpret_cast<const bf16x8*>((const char*)hs + aoff);
        #pragma unroll
        for (int t = 0; t < 4; ++t) {
            bf16x8 b = *reinterpret_cast<const bf16x8*>(
                    WT + (long)(col0 + t * 16 + lo) * H_DIM + k0 + hi * 8);
            acc[t] = __builtin_amdgcn_mfma_f32_16x16x32_bf16(a, b, acc[t], 0, 0, 0);
        }
    }

    // ---- epilogue: residual + relu -> Xout ----
    #pragma unroll
    for (int t = 0; t < 4; ++t) {
        const int col = col0 + t * 16 + lo;
        #pragma unroll
        for (int r = 0; r < 4; ++r) {
            const int rl  = hi * 4 + r;
            const int row = bm + rl;
            const int hoff = rl * 512 + ((col * 2) ^ ((rl & 7) << 4));
            float hv = bf2f(*reinterpret_cast<const u16*>((const char*)hs + hoff));
            long idx = (long)row * H_DIM + col;
            float v = (1.f - beta) * hv + beta * acc[t][r] + bf2f(Xin[idx]);
            Xout[idx] = f2bf(fmaxf(v, 0.f));
        }
    }
}

// ---------------- MFMA GEMM (lin0 / lin1), unchanged from R8 ----------------
// MODE 0 (lin0): A fp32; X=X0=relu(acc+bias)
// MODE 2 (lin1): A=X bf16; out=acc+bias for col<C_OUT
template <int K, int NT, int MODE>
__global__ __launch_bounds__(256) void mfma_gemm_kernel(
        const void* __restrict__ Aptr, const u16* __restrict__ WT,
        const float* __restrict__ bias,
        u16* __restrict__ X, u16* __restrict__ X0, float* __restrict__ out) {
    const int w  = threadIdx.x >> 6;
    const int l  = threadIdx.x & 63;
    const int hi = l >> 4, lo = l & 15;
    const int bm = blockIdx.x * 16;
    const int col0 = w * (NT * 16);

    f32x4 acc[NT];
    #pragma unroll
    for (int t = 0; t < NT; ++t) acc[t] = (f32x4){0.f, 0.f, 0.f, 0.f};

    for (int k0 = 0; k0 < K; k0 += 32) {
        bf16x8 a;
        if (MODE == 0) {
            const float* ap = (const float*)Aptr + (long)(bm + lo) * K + k0 + hi * 8;
            float4 f0 = *reinterpret_cast<const float4*>(ap);
            float4 f1 = *reinterpret_cast<const float4*>(ap + 4);
            a[0] = (short)f2bf(f0.x); a[1] = (short)f2bf(f0.y);
            a[2] = (short)f2bf(f0.z); a[3] = (short)f2bf(f0.w);
            a[4] = (short)f2bf(f1.x); a[5] = (short)f2bf(f1.y);
            a[6] = (short)f2bf(f1.z); a[7] = (short)f2bf(f1.w);
        } else {
            a = *reinterpret_cast<const bf16x8*>(
                    (const u16*)Aptr + (long)(bm + lo) * K + k0 + hi * 8);
        }
        #pragma unroll
        for (int t = 0; t < NT; ++t) {
            bf16x8 b = *reinterpret_cast<const bf16x8*>(
                    WT + (long)(col0 + t * 16 + lo) * K + k0 + hi * 8);
            acc[t] = __builtin_amdgcn_mfma_f32_16x16x32_bf16(a, b, acc[t], 0, 0, 0);
        }
    }

    #pragma unroll
    for (int t = 0; t < NT; ++t) {
        const int col = col0 + t * 16 + lo;
        #pragma unroll
        for (int r = 0; r < 4; ++r) {
            const int row = bm + hi * 4 + r;
            float v = acc[t][r];
            if (MODE == 0) {
                v = fmaxf(v + bias[col], 0.f);
                u16 h = f2bf(v);
                long idx = (long)row * H_DIM + col;
                X[idx] = h; X0[idx] = h;
            } else {
                if (col < C_OUT) out[(long)row * C_OUT + col] = v + bias[col];
            }
        }
    }
}

extern "C" void kernel_launch(void* const* d_in, const int* in_sizes, int n_in,
                              void* d_out, int out_size, void* d_ws, size_t ws_size,
                              hipStream_t stream) {
    const float* x_in = (const float*)d_in[0];
    const int*   esrc = (const int*)d_in[1];
    const int*   edst = (const int*)d_in[2];
    const float* ew   = (const float*)d_in[3];
    const float* l0w  = (const float*)d_in[4];
    const float* l0b  = (const float*)d_in[5];
    const float* cw   = (const float*)d_in[6];
    const float* l1w  = (const float*)d_in[7];
    const float* l1b  = (const float*)d_in[8];
    float* out = (float*)d_out;
    (void)in_sizes; (void)n_in; (void)out_size;

    char* ws = (char*)d_ws;
    auto al = [](size_t x) { return (x + 255) & ~(size_t)255; };
    size_t o = 0;
    const size_t NHb = (size_t)N_NODES * H_DIM * sizeof(u16);    // 25.6 MB
    u16* Xa = (u16*)(ws + o);  o += al(NHb);
    u16* Xb = (u16*)(ws + o);  o += al(NHb);
    u16* X0 = (u16*)(ws + o);  o += al(NHb);
    int* row_ptr = (int*)(ws + o); o += al((N_NODES + 1) * sizeof(int));
    int* cnt     = (int*)(ws + o); o += al((size_t)N_NODES * sizeof(int));
    int* s_src   = (int*)(ws + o); o += al((size_t)E_EDGES * sizeof(int));
    float* s_w   = (float*)(ws + o); o += al((size_t)E_EDGES * sizeof(float));
    u16* WT0 = (u16*)(ws + o); o += al((size_t)H_DIM * F_INDIM * sizeof(u16));          // 256 KB
    u16* WTc = (u16*)(ws + o); o += al((size_t)L_LAYERS * H_DIM * H_DIM * sizeof(u16)); // 512 KB
    u16* WT1 = (u16*)(ws + o); o += al((size_t)128 * H_DIM * sizeof(u16));              // 64 KB
    if (ws_size < o) return;   // diagnostic: clean zero-output => ws too small

    const int MBLK = N_NODES / 16;   // 3125, exact

    // 0. weight prep: transpose + bf16-convert
    transpose_kernel<<<(H_DIM * F_INDIM + 255) / 256, 256, 0, stream>>>(
        l0w, WT0, F_INDIM, H_DIM, H_DIM);
    for (int l = 0; l < L_LAYERS; ++l)
        transpose_kernel<<<(H_DIM * H_DIM + 255) / 256, 256, 0, stream>>>(
            cw + (size_t)l * H_DIM * H_DIM, WTc + (size_t)l * H_DIM * H_DIM,
            H_DIM, H_DIM, H_DIM);
    transpose_kernel<<<(128 * H_DIM + 255) / 256, 256, 0, stream>>>(
        l1w, WT1, H_DIM, C_OUT, 128);

    // 1. input projection: Xa = X0 = relu(x_in @ l0w + l0b)   [MFMA]
    mfma_gemm_kernel<F_INDIM, 4, 0><<<MBLK, 256, 0, stream>>>(
        x_in, WT0, l0b, Xa, X0, nullptr);

    // 2. CSR build
    zeroi_kernel<<<(N_NODES + 255) / 256, 256, 0, stream>>>(cnt, N_NODES);
    hist_kernel<<<(E_EDGES + 255) / 256, 256, 0, stream>>>(edst, cnt);
    scan_kernel<<<1, 256, 0, stream>>>(cnt, row_ptr);
    zeroi_kernel<<<(N_NODES + 255) / 256, 256, 0, stream>>>(cnt, N_NODES);
    scatter_kernel<<<(E_EDGES + 255) / 256, 256, 0, stream>>>(esrc, edst, ew, row_ptr,
                                                              cnt, s_src, s_w);

    // 3. fused layers, ping-pong Xa <-> Xb
    u16* Xcur = Xa;
    u16* Xnxt = Xb;
    for (int l = 0; l < L_LAYERS; ++l) {
        float beta = logf(1.0f / (float)(l + 1) + 1.0f);
        layer_kernel<<<MBLK, 256, 0, stream>>>(row_ptr, s_src, s_w, Xcur, X0, Xnxt,
                                               WTc + (size_t)l * H_DIM * H_DIM, beta);
        u16* tmp = Xcur; Xcur = Xnxt; Xnxt = tmp;
    }

    // 4. output projection: out = Xcur @ l1w + l1b   [MFMA]
    mfma_gemm_kernel<H_DIM, 2, 2><<<MBLK, 256, 0, stream>>>(
        Xcur, WT1, l1b, nullptr, nullptr, out);
}